// Round 12
// baseline (268.439 us; speedup 1.0000x reference)
//
#include <hip/hip_runtime.h>
#include <hip/hip_bf16.h>
#include <stdint.h>

#define IN_F 128
#define EDGE_F 6
#define ROWS 64          // dst nodes per block in agg_gemm
#define RSTRIDE 136      // LDS S-tile row stride in ushorts (272B: 2-way-free banks)

using bf16x8 = __attribute__((ext_vector_type(8))) short;  // 8 bf16 = 4 VGPRs
using f32x4  = __attribute__((ext_vector_type(4))) float;

__device__ __forceinline__ float bf2f(unsigned short u) {
    return __uint_as_float(((unsigned int)u) << 16);
}
__device__ __forceinline__ unsigned short f2bfbits(float f) {
    __hip_bfloat16 h = __float2bfloat16(f);  // RNE
    return *reinterpret_cast<unsigned short*>(&h);
}
__device__ __forceinline__ unsigned int packbf(float a, float b) {
    return ((unsigned int)f2bfbits(b) << 16) | (unsigned int)f2bfbits(a);
}

// ---- Phase 1: histogram (atomic return = rank) + CSR-payload pre-pack + nf cast ----
// The scattered atomic stream is TCC-RMW-rate-bound (~19 G/s) with VALU+HBM
// mostly idle, so the ef read/pack and nf->bf16 cast ride along ~free.
__global__ __launch_bounds__(256) void hist_cast(
        const int* __restrict__ eidx, const float* __restrict__ ef,
        int* __restrict__ cnt, int* __restrict__ rank,
        uint4* __restrict__ efp, int n_edges,
        const float* __restrict__ nf, unsigned short* __restrict__ nfb,
        int n_cast) {  // n_cast = N*128/8 ushort8 units
    const int t = blockIdx.x * 256 + threadIdx.x;
    if (t < n_edges) {
        const int2 pr = reinterpret_cast<const int2*>(eidx)[t];  // (src, dst)
        const float2* efs = reinterpret_cast<const float2*>(ef + (size_t)t * EDGE_F);
        const float2 f0 = efs[0], f1 = efs[1], f2 = efs[2];
        uint4 q;
        q.x = (unsigned int)pr.x;
        q.y = packbf(f0.x, f0.y);
        q.z = packbf(f1.x, f1.y);
        q.w = packbf(f2.x, f2.y);
        efp[t] = q;                               // coalesced 16B, e-order
        rank[t] = atomicAdd(&cnt[pr.y], 1);       // the one scattered atomic
    }
    const int stride = gridDim.x * 256;
    for (int i = t; i < n_cast; i += stride) {
        const float4 lo = reinterpret_cast<const float4*>(nf)[2 * i];
        const float4 hi = reinterpret_cast<const float4*>(nf)[2 * i + 1];
        uint4 o;
        o.x = packbf(lo.x, lo.y); o.y = packbf(lo.z, lo.w);
        o.z = packbf(hi.x, hi.y); o.w = packbf(hi.z, hi.w);
        reinterpret_cast<uint4*>(nfb)[i] = o;
    }
}

// ---- Phase 2: single-dispatch decoupled-lookback scan + weight pack ----
// Grid = nblk+1 = 197 blocks <= 256 CUs: all blocks get a CU immediately, so
// the lookback spin is safe (verified R9/R11). NOT cooperative — R10 showed
// grid.sync() costs ~100us/sync at full-machine grids.
__global__ __launch_bounds__(256) void scan_fused(
        const int* __restrict__ cnt, int* __restrict__ rowptr, int n, int nblk,
        unsigned long long* __restrict__ agg,
        const float* __restrict__ W, const float* __restrict__ b,
        const float* __restrict__ We, const float* __restrict__ be,
        unsigned short* __restrict__ Wpack, float* __restrict__ W2pack) {
    const int tid = threadIdx.x;
    const int blk = blockIdx.x;
    if (blk == nblk) {  // weight-pack block
        // Wpack: idx=((kb*8+ft)*64+lane)*8+j -> bf16(W[kb*32+(lane>>4)*8+j][ft*16+(lane&15)])
        for (int idx = tid; idx < 16384; idx += 256) {
            int j = idx & 7, lane = (idx >> 3) & 63, ft = (idx >> 9) & 7, kb = idx >> 12;
            int k = kb * 32 + (lane >> 4) * 8 + j;
            int f = ft * 16 + (lane & 15);
            Wpack[idx] = f2bfbits(W[k * 128 + f]);
        }
        for (int idx = tid; idx < 1024; idx += 256) {
            int j = idx >> 7, f = idx & 127;
            float w = 0.f;
            if (j < 6)       w = We[j * 128 + f];
            else if (j == 6) w = b[f] + be[f];
            W2pack[idx] = w;
        }
        return;
    }
    __shared__ int sh[256];
    const int idx = blk * 256 + tid;
    const int v = (idx < n) ? cnt[idx] : 0;
    sh[tid] = v;
    __syncthreads();
    for (int off = 1; off < 256; off <<= 1) {  // inclusive scan
        int t2 = (tid >= off) ? sh[tid - off] : 0;
        __syncthreads();
        sh[tid] += t2;
        __syncthreads();
    }
    const int incl = sh[tid];
    if (tid == 0)  // publish block total ASAP (device-scope atomic)
        atomicExch(&agg[blk], (1ULL << 32) | (unsigned int)sh[255]);
    int pre = 0;
    if (tid < blk) {  // parallel lookback, co-residency guaranteed
        unsigned long long x;
        do { x = atomicAdd(&agg[tid], 0ULL); } while ((x >> 32) == 0);
        pre = (int)(unsigned int)x;
    }
    __syncthreads();
    sh[tid] = pre;
    __syncthreads();
    for (int off = 128; off > 0; off >>= 1) {  // reduce predecessor aggregates
        if (tid < off) sh[tid] += sh[tid + off];
        __syncthreads();
    }
    const int off0 = sh[0];
    if (idx < n) rowptr[idx] = off0 + incl - v;            // exclusive prefix
    if (blk == nblk - 1 && tid == 255) rowptr[n] = off0 + incl;
}

// ---- Phase 3: pure permutation scatter: rec[rowptr[dst]+rank[e]] = efp[e] ----
__global__ __launch_bounds__(256) void fill_csr(
        const int* __restrict__ eidx, const int* __restrict__ rowptr,
        const int* __restrict__ rank, const uint4* __restrict__ efp,
        uint4* __restrict__ rec, int n_edges) {
    int e = blockIdx.x * 256 + threadIdx.x;
    if (e >= n_edges) return;
    const int dst = reinterpret_cast<const int2*>(eidx)[e].y;
    const int pos = rowptr[dst] + rank[e];          // rowptr: 200KB, L2-hot
    rec[pos] = efp[e];                              // 16B gather->scatter
}

// ---- Phase 4+5 fused: aggregate into LDS, then MFMA GEMM from LDS ----
// Block = 256 threads owns 64 dst nodes. Phase A: 4 waves x 16 nodes each,
// wave-per-node gather (8-deep, rec loads wave-uniform -> SGPR), S tile ->
// LDS (row stride 272B: dword bank = (68r+lane)%32, 2-way aliasing = free).
// Phase B: the R6-verified MFMA tile; A-frags ds_read_b128 from Sl, B-frags
// streamed from L2-resident Wpack (32KB shared by all blocks; no LDS staging
// keeps LDS at 18.5KB so occupancy stays VGPR-bound ~5 blocks/CU like R11's
// aggregate). Kills the gemm dispatch + S/E8 global round-trip.
__global__ __launch_bounds__(256) void agg_gemm(
        const unsigned short* __restrict__ nfb, const uint4* __restrict__ rec,
        const int* __restrict__ rowptr,
        const unsigned short* __restrict__ Wpack, const float* __restrict__ W2pack,
        float* __restrict__ out, int n_nodes) {
    __shared__ __align__(16) unsigned short Sl[ROWS * RSTRIDE];  // 17408 B
    __shared__ __align__(16) unsigned short E8l[ROWS * 8];       // 1024 B
    const int tid = threadIdx.x;
    const int lane = tid & 63;
    const int wv = tid >> 6;  // 0..3
    const int nb0 = blockIdx.x * ROWS;

    // ---- Phase A: aggregate 64 nodes (wave per node, 16 per wave) ----
    for (int r = wv; r < ROWS; r += 4) {
        const int n = nb0 + r;
        float ax = 0.f, ay = 0.f;
        float e0 = 0.f, e1 = 0.f, e2 = 0.f, e3 = 0.f, e4 = 0.f, e5 = 0.f;
        int deg = 0;
        if (n < n_nodes) {
            const int r0 = rowptr[n], r1 = rowptr[n + 1];
            deg = r1 - r0;
            int i = r0;
            for (; i + 7 < r1; i += 8) {  // 8 gathers in flight
                uint4 q[8];
                unsigned int u[8];
#pragma unroll
                for (int j = 0; j < 8; ++j) q[j] = rec[i + j];  // SGPR, wave-uniform
#pragma unroll
                for (int j = 0; j < 8; ++j)
                    u[j] = reinterpret_cast<const unsigned int*>(nfb + (size_t)(int)q[j].x * IN_F)[lane];
#pragma unroll
                for (int j = 0; j < 8; ++j) {
                    ax += bf2f((unsigned short)u[j]);
                    ay += bf2f((unsigned short)(u[j] >> 16));
                    e0 += bf2f((unsigned short)q[j].y);
                    e1 += bf2f((unsigned short)(q[j].y >> 16));
                    e2 += bf2f((unsigned short)q[j].z);
                    e3 += bf2f((unsigned short)(q[j].z >> 16));
                    e4 += bf2f((unsigned short)q[j].w);
                    e5 += bf2f((unsigned short)(q[j].w >> 16));
                }
            }
            for (; i + 3 < r1; i += 4) {
                uint4 q[4];
                unsigned int u[4];
#pragma unroll
                for (int j = 0; j < 4; ++j) q[j] = rec[i + j];
#pragma unroll
                for (int j = 0; j < 4; ++j)
                    u[j] = reinterpret_cast<const unsigned int*>(nfb + (size_t)(int)q[j].x * IN_F)[lane];
#pragma unroll
                for (int j = 0; j < 4; ++j) {
                    ax += bf2f((unsigned short)u[j]);
                    ay += bf2f((unsigned short)(u[j] >> 16));
                    e0 += bf2f((unsigned short)q[j].y);
                    e1 += bf2f((unsigned short)(q[j].y >> 16));
                    e2 += bf2f((unsigned short)q[j].z);
                    e3 += bf2f((unsigned short)(q[j].z >> 16));
                    e4 += bf2f((unsigned short)q[j].w);
                    e5 += bf2f((unsigned short)(q[j].w >> 16));
                }
            }
            for (; i < r1; ++i) {
                const uint4 q0 = rec[i];
                const unsigned int u0 = reinterpret_cast<const unsigned int*>(nfb + (size_t)(int)q0.x * IN_F)[lane];
                ax += bf2f((unsigned short)u0); ay += bf2f((unsigned short)(u0 >> 16));
                e0 += bf2f((unsigned short)q0.y); e1 += bf2f((unsigned short)(q0.y >> 16));
                e2 += bf2f((unsigned short)q0.z); e3 += bf2f((unsigned short)(q0.z >> 16));
                e4 += bf2f((unsigned short)q0.w); e5 += bf2f((unsigned short)(q0.w >> 16));
            }
        }
        reinterpret_cast<unsigned int*>(Sl + r * RSTRIDE)[lane] = packbf(ax, ay);
        if (lane == 0) {
            uint4 q;
            q.x = packbf(e0, e1);
            q.y = packbf(e2, e3);
            q.z = packbf(e4, e5);
            q.w = packbf((float)deg, 0.f);      // deg exact in bf16 (small)
            *reinterpret_cast<uint4*>(E8l + r * 8) = q;
        }
    }
    __syncthreads();

    // ---- Phase B: 16x128 MFMA tile per wave (rows wv*16 .. wv*16+15) ----
    const int m = lane & 15, quad = lane >> 4;
    const int rbase = wv * 16;

    const unsigned short* ap = Sl + (rbase + m) * RSTRIDE + quad * 8;
    bf16x8 a[4];
#pragma unroll
    for (int kb = 0; kb < 4; ++kb)
        a[kb] = *reinterpret_cast<const bf16x8*>(ap + kb * 32);

    f32x4 acc[8];
#pragma unroll
    for (int ft = 0; ft < 8; ++ft) acc[ft] = (f32x4){0.f, 0.f, 0.f, 0.f};

#pragma unroll
    for (int kb = 0; kb < 4; ++kb) {
#pragma unroll
        for (int ft = 0; ft < 8; ++ft) {
            const bf16x8 bfrag =
                reinterpret_cast<const bf16x8*>(Wpack)[(kb * 8 + ft) * 64 + lane];
            acc[ft] = __builtin_amdgcn_mfma_f32_16x16x32_bf16(a[kb], bfrag, acc[ft], 0, 0, 0);
        }
    }

    // Epilogue. C/D layout: col=lane&15, row=quad*4+reg.
    float e[4][7];
#pragma unroll
    for (int r = 0; r < 4; ++r) {
        const int rl = rbase + quad * 4 + r;
        const uint4 q = *reinterpret_cast<const uint4*>(E8l + rl * 8);
        e[r][0] = bf2f((unsigned short)q.x); e[r][1] = bf2f((unsigned short)(q.x >> 16));
        e[r][2] = bf2f((unsigned short)q.y); e[r][3] = bf2f((unsigned short)(q.y >> 16));
        e[r][4] = bf2f((unsigned short)q.z); e[r][5] = bf2f((unsigned short)(q.z >> 16));
        e[r][6] = bf2f((unsigned short)q.w);  // deg
    }
#pragma unroll
    for (int ft = 0; ft < 8; ++ft) {
        const int f = ft * 16 + m;
        float w2[7];
#pragma unroll
        for (int j = 0; j < 7; ++j) w2[j] = W2pack[j * 128 + f];  // L2-hot
#pragma unroll
        for (int r = 0; r < 4; ++r) {
            const int n = nb0 + rbase + quad * 4 + r;
            if (n < n_nodes) {
                float v = acc[ft][r];
#pragma unroll
                for (int j = 0; j < 7; ++j) v += e[r][j] * w2[j];
                out[(size_t)n * 128 + f] = fmaxf(v, 0.f);
            }
        }
    }
}

extern "C" void kernel_launch(void* const* d_in, const int* in_sizes, int n_in,
                              void* d_out, int out_size, void* d_ws, size_t ws_size,
                              hipStream_t stream) {
    const float* nf = (const float*)d_in[0];  // fp32 (N,128)
    const int* eidx = (const int*)d_in[1];    // int32 (E,2)
    const float* ef = (const float*)d_in[2];  // fp32 (E,6)
    const float* W  = (const float*)d_in[3];  // fp32 (128,128)
    const float* b  = (const float*)d_in[4];  // fp32 (128,)
    const float* We = (const float*)d_in[5];  // fp32 (6,128)
    const float* be = (const float*)d_in[6];  // fp32 (128,)
    float* out = (float*)d_out;               // fp32 (N,128)

    const int n_nodes = in_sizes[0] / IN_F;
    const int n_edges = in_sizes[1] / 2;

    // ws (~40 MB; ws_size ~268 MB per harness poison WRITE_SIZE):
    // rec 16B*E | efp 16B*E | Wpack 32KB | W2pack 4KB
    //   | cnt N | agg 256 ull | rowptr N+1 | rank E | nfb bf16 N*128
    uint4* rec = (uint4*)d_ws;
    uint4* efp = rec + n_edges;
    unsigned short* Wpack = (unsigned short*)(efp + n_edges);
    float* W2pack = (float*)(Wpack + 16384);
    int* cnt = (int*)(W2pack + 1024);
    unsigned long long* agg = (unsigned long long*)(cnt + n_nodes);
    int* rowptr = (int*)(agg + 256);
    int* rank   = rowptr + n_nodes + 1;
    unsigned short* nfb = (unsigned short*)(rank + n_edges);

    // zero cnt + agg flags in one memset (contiguous)
    hipMemsetAsync(cnt, 0, (size_t)n_nodes * 4 + 256 * 8, stream);

    const int eb = (n_edges + 255) / 256;
    const int nblk = (n_nodes + 255) / 256;  // 196 scan blocks (+1 pack block)
    const int n_cast = n_nodes * (IN_F / 8);

    hist_cast<<<eb, 256, 0, stream>>>(eidx, ef, cnt, rank, efp, n_edges, nf, nfb, n_cast);
    scan_fused<<<nblk + 1, 256, 0, stream>>>(cnt, rowptr, n_nodes, nblk, agg,
                                             W, b, We, be, Wpack, W2pack);
    fill_csr<<<eb, 256, 0, stream>>>(eidx, rowptr, rank, efp, rec, n_edges);

    agg_gemm<<<(n_nodes + ROWS - 1) / ROWS, 256, 0, stream>>>(
        nfb, rec, rowptr, Wpack, W2pack, out, n_nodes);
}

// Round 13
// 206.299 us; speedup vs baseline: 1.3012x; 1.3012x over previous
//
#include <hip/hip_runtime.h>
#include <hip/hip_bf16.h>
#include <stdint.h>

#define IN_F 128
#define EDGE_F 6

using bf16x8 = __attribute__((ext_vector_type(8))) short;  // 8 bf16 = 4 VGPRs
using f32x4  = __attribute__((ext_vector_type(4))) float;

__device__ __forceinline__ float bf2f(unsigned short u) {
    return __uint_as_float(((unsigned int)u) << 16);
}
__device__ __forceinline__ unsigned short f2bfbits(float f) {
    __hip_bfloat16 h = __float2bfloat16(f);  // RNE
    return *reinterpret_cast<unsigned short*>(&h);
}
__device__ __forceinline__ unsigned int packbf(float a, float b) {
    return ((unsigned int)f2bfbits(b) << 16) | (unsigned int)f2bfbits(a);
}

// ---- Phase 1: histogram (atomic return = rank) + CSR-payload pre-pack + nf cast ----
// The scattered atomic stream is TCC-RMW-rate-bound (~19 G/s) with VALU+HBM
// mostly idle, so the ef read/pack and nf->bf16 cast ride along ~free.
__global__ __launch_bounds__(256) void hist_cast(
        const int* __restrict__ eidx, const float* __restrict__ ef,
        int* __restrict__ cnt, int* __restrict__ rank,
        uint4* __restrict__ efp, int n_edges,
        const float* __restrict__ nf, unsigned short* __restrict__ nfb,
        int n_cast) {  // n_cast = N*128/8 ushort8 units
    const int t = blockIdx.x * 256 + threadIdx.x;
    if (t < n_edges) {
        const int2 pr = reinterpret_cast<const int2*>(eidx)[t];  // (src, dst)
        const float2* efs = reinterpret_cast<const float2*>(ef + (size_t)t * EDGE_F);
        const float2 f0 = efs[0], f1 = efs[1], f2 = efs[2];
        uint4 q;
        q.x = (unsigned int)pr.x;
        q.y = packbf(f0.x, f0.y);
        q.z = packbf(f1.x, f1.y);
        q.w = packbf(f2.x, f2.y);
        efp[t] = q;                               // coalesced 16B, e-order
        rank[t] = atomicAdd(&cnt[pr.y], 1);       // the one scattered atomic
    }
    const int stride = gridDim.x * 256;
    for (int i = t; i < n_cast; i += stride) {
        const float4 lo = reinterpret_cast<const float4*>(nf)[2 * i];
        const float4 hi = reinterpret_cast<const float4*>(nf)[2 * i + 1];
        uint4 o;
        o.x = packbf(lo.x, lo.y); o.y = packbf(lo.z, lo.w);
        o.z = packbf(hi.x, hi.y); o.w = packbf(hi.z, hi.w);
        reinterpret_cast<uint4*>(nfb)[i] = o;
    }
}

// ---- Phase 2: single-dispatch decoupled-lookback scan + weight pack ----
// Grid = nblk+1 = 197 blocks <= 256 CUs: all blocks get a CU immediately, so
// the lookback spin is safe (verified R9/R11). NOT cooperative — R10 showed
// grid.sync() costs ~100us/sync at full-machine grids.
__global__ __launch_bounds__(256) void scan_fused(
        const int* __restrict__ cnt, int* __restrict__ rowptr, int n, int nblk,
        unsigned long long* __restrict__ agg,
        const float* __restrict__ W, const float* __restrict__ b,
        const float* __restrict__ We, const float* __restrict__ be,
        unsigned short* __restrict__ Wpack, float* __restrict__ W2pack) {
    const int tid = threadIdx.x;
    const int blk = blockIdx.x;
    if (blk == nblk) {  // weight-pack block
        // Wpack: idx=((kb*8+ft)*64+lane)*8+j -> bf16(W[kb*32+(lane>>4)*8+j][ft*16+(lane&15)])
        for (int idx = tid; idx < 16384; idx += 256) {
            int j = idx & 7, lane = (idx >> 3) & 63, ft = (idx >> 9) & 7, kb = idx >> 12;
            int k = kb * 32 + (lane >> 4) * 8 + j;
            int f = ft * 16 + (lane & 15);
            Wpack[idx] = f2bfbits(W[k * 128 + f]);
        }
        for (int idx = tid; idx < 1024; idx += 256) {
            int j = idx >> 7, f = idx & 127;
            float w = 0.f;
            if (j < 6)       w = We[j * 128 + f];
            else if (j == 6) w = b[f] + be[f];
            W2pack[idx] = w;
        }
        return;
    }
    __shared__ int sh[256];
    const int idx = blk * 256 + tid;
    const int v = (idx < n) ? cnt[idx] : 0;
    sh[tid] = v;
    __syncthreads();
    for (int off = 1; off < 256; off <<= 1) {  // inclusive scan
        int t2 = (tid >= off) ? sh[tid - off] : 0;
        __syncthreads();
        sh[tid] += t2;
        __syncthreads();
    }
    const int incl = sh[tid];
    if (tid == 0)  // publish block total ASAP (device-scope atomic)
        atomicExch(&agg[blk], (1ULL << 32) | (unsigned int)sh[255]);
    // Parallel lookback: thread t spins on predecessor t (t < blk).
    int pre = 0;
    if (tid < blk) {
        unsigned long long x;
        do { x = atomicAdd(&agg[tid], 0ULL); } while ((x >> 32) == 0);
        pre = (int)(unsigned int)x;
    }
    __syncthreads();  // done with sh as scan buffer
    sh[tid] = pre;
    __syncthreads();
    for (int off = 128; off > 0; off >>= 1) {  // reduce predecessor aggregates
        if (tid < off) sh[tid] += sh[tid + off];
        __syncthreads();
    }
    const int off0 = sh[0];
    if (idx < n) rowptr[idx] = off0 + incl - v;            // exclusive prefix
    if (blk == nblk - 1 && tid == 255) rowptr[n] = off0 + incl;
}

// ---- Phase 3: pure permutation scatter: rec[rowptr[dst]+rank[e]] = efp[e] ----
__global__ __launch_bounds__(256) void fill_csr(
        const int* __restrict__ eidx, const int* __restrict__ rowptr,
        const int* __restrict__ rank, const uint4* __restrict__ efp,
        uint4* __restrict__ rec, int n_edges) {
    int e = blockIdx.x * 256 + threadIdx.x;
    if (e >= n_edges) return;
    const int dst = reinterpret_cast<const int2*>(eidx)[e].y;
    const int pos = rowptr[dst] + rank[e];          // rowptr: 200KB, L2-hot
    rec[pos] = efp[e];                              // 16B gather->scatter
}

// ---- Phase 4: aggregate, bf16 gather (256B rows). One 64-lane wave per dst. ----
// rec[i] loads are wave-uniform -> SGPRs (cheap), so an 8-deep unroll puts 8
// vector gathers in flight per wave (~150 outstanding/CU at 18 waves/CU) to
// fill the L2/LLC pipeline. Max-occupancy kernel (16 VGPR): do NOT fuse with
// the MFMA gemm — R12 showed fusion collapses wave count 50000->3128 and
// doubles total time.
__global__ __launch_bounds__(256) void aggregate_bf16(
        const unsigned short* __restrict__ nfb, const uint4* __restrict__ rec,
        const int* __restrict__ rowptr, unsigned short* __restrict__ S,
        unsigned short* __restrict__ E8, int n_nodes) {
    const int lane = threadIdx.x & 63;
    const int wv = __builtin_amdgcn_readfirstlane(threadIdx.x >> 6);
    const int n = blockIdx.x * 4 + wv;
    if (n >= n_nodes) return;
    const int r0 = rowptr[n], r1 = rowptr[n + 1];
    const int deg = r1 - r0;
    float ax = 0.f, ay = 0.f;
    float e0 = 0.f, e1 = 0.f, e2 = 0.f, e3 = 0.f, e4 = 0.f, e5 = 0.f;
    int i = r0;
    for (; i + 7 < r1; i += 8) {  // 8 gathers in flight
        uint4 q[8];
        unsigned int u[8];
#pragma unroll
        for (int j = 0; j < 8; ++j) q[j] = rec[i + j];           // SGPR, wave-uniform
#pragma unroll
        for (int j = 0; j < 8; ++j)
            u[j] = reinterpret_cast<const unsigned int*>(nfb + (size_t)(int)q[j].x * IN_F)[lane];
#pragma unroll
        for (int j = 0; j < 8; ++j) {
            ax += bf2f((unsigned short)u[j]);
            ay += bf2f((unsigned short)(u[j] >> 16));
            e0 += bf2f((unsigned short)q[j].y);
            e1 += bf2f((unsigned short)(q[j].y >> 16));
            e2 += bf2f((unsigned short)q[j].z);
            e3 += bf2f((unsigned short)(q[j].z >> 16));
            e4 += bf2f((unsigned short)q[j].w);
            e5 += bf2f((unsigned short)(q[j].w >> 16));
        }
    }
    for (; i + 3 < r1; i += 4) {  // 4-deep tail
        uint4 q[4];
        unsigned int u[4];
#pragma unroll
        for (int j = 0; j < 4; ++j) q[j] = rec[i + j];
#pragma unroll
        for (int j = 0; j < 4; ++j)
            u[j] = reinterpret_cast<const unsigned int*>(nfb + (size_t)(int)q[j].x * IN_F)[lane];
#pragma unroll
        for (int j = 0; j < 4; ++j) {
            ax += bf2f((unsigned short)u[j]);
            ay += bf2f((unsigned short)(u[j] >> 16));
            e0 += bf2f((unsigned short)q[j].y);
            e1 += bf2f((unsigned short)(q[j].y >> 16));
            e2 += bf2f((unsigned short)q[j].z);
            e3 += bf2f((unsigned short)(q[j].z >> 16));
            e4 += bf2f((unsigned short)q[j].w);
            e5 += bf2f((unsigned short)(q[j].w >> 16));
        }
    }
    for (; i < r1; ++i) {
        const uint4 q0 = rec[i];
        const unsigned int u0 = reinterpret_cast<const unsigned int*>(nfb + (size_t)(int)q0.x * IN_F)[lane];
        ax += bf2f((unsigned short)u0); ay += bf2f((unsigned short)(u0 >> 16));
        e0 += bf2f((unsigned short)q0.y); e1 += bf2f((unsigned short)(q0.y >> 16));
        e2 += bf2f((unsigned short)q0.z); e3 += bf2f((unsigned short)(q0.z >> 16));
        e4 += bf2f((unsigned short)q0.w); e5 += bf2f((unsigned short)(q0.w >> 16));
    }
    unsigned short* row = S + (size_t)n * IN_F;
    reinterpret_cast<unsigned int*>(row)[lane] = packbf(ax, ay);
    if (lane == 0) {
        uint4 q;
        q.x = packbf(e0, e1);
        q.y = packbf(e2, e3);
        q.z = packbf(e4, e5);
        q.w = packbf((float)deg, 0.f);          // deg exact in bf16 (small)
        *reinterpret_cast<uint4*>(E8 + (size_t)n * 8) = q;
    }
}

// ---- Phase 5: MFMA GEMM  out = relu( S[N,128]bf16 @ W[128,128]bf16 + E-term ) ----
__global__ __launch_bounds__(256) void gemm_mfma(
        const unsigned short* __restrict__ S, const unsigned short* __restrict__ E8,
        const unsigned short* __restrict__ Wpack, const float* __restrict__ W2pack,
        float* __restrict__ out, int n_nodes) {
    __shared__ __align__(16) short Wl[16384];   // 32 KB, B-fragment layout
    __shared__ float W2l[1024];                 // 4 KB
    const int tid = threadIdx.x;
    for (int i = tid; i < 2048; i += 256)
        reinterpret_cast<uint4*>(Wl)[i] = reinterpret_cast<const uint4*>(Wpack)[i];
    for (int i = tid; i < 1024; i += 256) W2l[i] = W2pack[i];

    const int wv = tid >> 6, lane = tid & 63;
    const int m = lane & 15, quad = lane >> 4;
    const int n0 = blockIdx.x * 64 + wv * 16;

    const int arow = min(n0 + m, n_nodes - 1);
    const unsigned short* ap = S + (size_t)arow * IN_F + quad * 8;
    bf16x8 a[4];
#pragma unroll
    for (int kb = 0; kb < 4; ++kb)
        a[kb] = *reinterpret_cast<const bf16x8*>(ap + kb * 32);

    __syncthreads();

    f32x4 acc[8];
#pragma unroll
    for (int ft = 0; ft < 8; ++ft) acc[ft] = (f32x4){0.f, 0.f, 0.f, 0.f};

#pragma unroll
    for (int kb = 0; kb < 4; ++kb) {
#pragma unroll
        for (int ft = 0; ft < 8; ++ft) {
            const bf16x8 bfrag =
                reinterpret_cast<const bf16x8*>(Wl)[(kb * 8 + ft) * 64 + lane];
            acc[ft] = __builtin_amdgcn_mfma_f32_16x16x32_bf16(a[kb], bfrag, acc[ft], 0, 0, 0);
        }
    }

    // Epilogue. C/D layout: col=lane&15, row=quad*4+reg.
    float e[4][7];
#pragma unroll
    for (int r = 0; r < 4; ++r) {
        const int n = min(n0 + quad * 4 + r, n_nodes - 1);
        const uint4 q = *reinterpret_cast<const uint4*>(E8 + (size_t)n * 8);
        e[r][0] = bf2f((unsigned short)q.x); e[r][1] = bf2f((unsigned short)(q.x >> 16));
        e[r][2] = bf2f((unsigned short)q.y); e[r][3] = bf2f((unsigned short)(q.y >> 16));
        e[r][4] = bf2f((unsigned short)q.z); e[r][5] = bf2f((unsigned short)(q.z >> 16));
        e[r][6] = bf2f((unsigned short)q.w);  // deg
    }
#pragma unroll
    for (int ft = 0; ft < 8; ++ft) {
        const int f = ft * 16 + m;
        float w2[7];
#pragma unroll
        for (int j = 0; j < 7; ++j) w2[j] = W2l[j * 128 + f];
#pragma unroll
        for (int r = 0; r < 4; ++r) {
            const int n = n0 + quad * 4 + r;
            if (n < n_nodes) {
                float v = acc[ft][r];
#pragma unroll
                for (int j = 0; j < 7; ++j) v += e[r][j] * w2[j];
                out[(size_t)n * 128 + f] = fmaxf(v, 0.f);
            }
        }
    }
}

extern "C" void kernel_launch(void* const* d_in, const int* in_sizes, int n_in,
                              void* d_out, int out_size, void* d_ws, size_t ws_size,
                              hipStream_t stream) {
    const float* nf = (const float*)d_in[0];  // fp32 (N,128)
    const int* eidx = (const int*)d_in[1];    // int32 (E,2)
    const float* ef = (const float*)d_in[2];  // fp32 (E,6)
    const float* W  = (const float*)d_in[3];  // fp32 (128,128)
    const float* b  = (const float*)d_in[4];  // fp32 (128,)
    const float* We = (const float*)d_in[5];  // fp32 (6,128)
    const float* be = (const float*)d_in[6];  // fp32 (128,)
    float* out = (float*)d_out;               // fp32 (N,128)

    const int n_nodes = in_sizes[0] / IN_F;
    const int n_edges = in_sizes[1] / 2;

    // ws (~53 MB; ws_size ~268 MB per harness poison WRITE_SIZE):
    // rec 16B*E | efp 16B*E | S bf16 N*128 | E8 | Wpack | W2pack
    //   | cnt N | agg 256 ull | rowptr N+1 | rank E | nfb bf16 N*128
    uint4* rec = (uint4*)d_ws;
    uint4* efp = rec + n_edges;
    unsigned short* S = (unsigned short*)(efp + n_edges);
    unsigned short* E8 = S + (size_t)n_nodes * IN_F;
    unsigned short* Wpack = E8 + (size_t)n_nodes * 8;
    float* W2pack = (float*)(Wpack + 16384);
    int* cnt = (int*)(W2pack + 1024);
    unsigned long long* agg = (unsigned long long*)(cnt + n_nodes);
    int* rowptr = (int*)(agg + 256);
    int* rank   = rowptr + n_nodes + 1;
    unsigned short* nfb = (unsigned short*)(rank + n_edges);

    // zero cnt + agg flags in one memset (contiguous)
    hipMemsetAsync(cnt, 0, (size_t)n_nodes * 4 + 256 * 8, stream);

    const int eb = (n_edges + 255) / 256;
    const int nblk = (n_nodes + 255) / 256;  // 196 scan blocks (+1 pack block)
    const int n_cast = n_nodes * (IN_F / 8);

    hist_cast<<<eb, 256, 0, stream>>>(eidx, ef, cnt, rank, efp, n_edges, nf, nfb, n_cast);
    scan_fused<<<nblk + 1, 256, 0, stream>>>(cnt, rowptr, n_nodes, nblk, agg,
                                             W, b, We, be, Wpack, W2pack);
    fill_csr<<<eb, 256, 0, stream>>>(eidx, rowptr, rank, efp, rec, n_edges);

    aggregate_bf16<<<(n_nodes + 3) / 4, 256, 0, stream>>>(nfb, rec, rowptr, S, E8, n_nodes);
    gemm_mfma<<<(n_nodes + 63) / 64, 256, 0, stream>>>(S, E8, Wpack, W2pack, out, n_nodes);
}